// Round 12
// baseline (266.356 us; speedup 1.0000x reference)
//
#include <hip/hip_runtime.h>

// VectorQuantizer: B=16, T=4096, D=256, K=1024 (fp32 in/out)
// N = B*T = 65536. out[n] = codebook[argmin_k ||x_n - c_k||^2]
//
// Two-tier (verified R6..R11 semantics):
//   1) bf16-split MFMA pass (16x16x32): codebook pre-scaled by -2 (exact),
//      split hi/lo bf16 once (prep), stored pre-swizzled; assign streams
//      16-code tiles through a 3-deep LDS pipeline fed by global_load_lds
//      with counted vmcnt(4) + raw s_barrier (never drain to 0 in-loop).
//      Terms (-2c)h.xh + (-2c)h.xl + (-2c)l.xh in 3 chains, chain0 seeded
//      with c2 -> m = c2 - 2*x.c. Per-point top-2; gap < EPS_FLAG -> recheck.
//   2) fp64 refine (bit-equivalent to round-6 PASS): direct-difference,
//      top-2, tie rule "runner-up within TIE_TOL=3.5e-5 and lower index".

#define DIMS   256
#define NCODE  1024
#define NPTS   65536
#define BMBLK  64           // points per block (4 waves x 16)
#define NT     64           // 16-code tiles
#define TB     16384        // bytes per tile buffer (hi 8K + lo 8K)
#define EPS_FLAG 8.0e-3f
#define TIE_TOL  3.5e-5
#define FLTMAX   3.402823466e+38f
#define CBT_OFF  327680     // byte offset of bf16 codebook tiles in d_ws

typedef __attribute__((ext_vector_type(8))) short bf16x8;   // 4 VGPR
typedef __attribute__((ext_vector_type(4))) float f32x4;    // 4 VGPR

// float*s -> bf16 (RNE) hi + exact-residual lo
__device__ __forceinline__ void cvt8s(const float4& a, const float4& b, float s,
                                      bf16x8& h, bf16x8& l) {
    float f[8] = {a.x*s, a.y*s, a.z*s, a.w*s, b.x*s, b.y*s, b.z*s, b.w*s};
    #pragma unroll
    for (int e = 0; e < 8; ++e) {
        unsigned u  = __float_as_uint(f[e]);
        unsigned hr = u + 0x7FFFu + ((u >> 16) & 1u);
        unsigned short hs = (unsigned short)(hr >> 16);
        float hf = __uint_as_float((unsigned)hs << 16);
        float lo = f[e] - hf;                       // exact
        unsigned ul = __float_as_uint(lo);
        unsigned lr = ul + 0x7FFFu + ((ul >> 16) & 1u);
        h[e] = (short)hs;
        l[e] = (short)(lr >> 16);
    }
}

// ---------- kernel P: cnt=0 + c2 (fp64) + codebook cvt to swizzled tiles ----
// Tile t (16 codes): base = t*16384; hi [0,8192), lo [8192,16384).
// Within: off(r,p) = (r*512 + p*16) ^ ((r&7)<<4), r = code&15, p = 8-dim chunk.
__global__ __launch_bounds__(256) void vq_prep_kernel(const float* __restrict__ cb,
                                                      float* __restrict__ c2f,
                                                      char* __restrict__ cbt,
                                                      int* __restrict__ cnt) {
    if (blockIdx.x == 0 && threadIdx.x == 0) cnt[0] = 0;
    const int chunk = blockIdx.x * 256 + threadIdx.x;    // [0, 32768)
    const int k = chunk >> 5;                            // code
    const int p = chunk & 31;                            // 8-dim chunk
    const float4* src = (const float4*)(cb + (size_t)k * DIMS + p * 8);
    float4 a = src[0], b = src[1];

    double s = (double)a.x*a.x + (double)a.y*a.y + (double)a.z*a.z + (double)a.w*a.w
             + (double)b.x*b.x + (double)b.y*b.y + (double)b.z*b.z + (double)b.w*b.w;
    #pragma unroll
    for (int off = 16; off > 0; off >>= 1) s += __shfl_xor(s, off, 64);
    if (p == 0) c2f[k] = (float)s;

    bf16x8 h, l;
    cvt8s(a, b, -2.0f, h, l);
    const int t = k >> 4, r = k & 15;
    const int soff = (r * 512 + p * 16) ^ ((r & 7) << 4);
    *(bf16x8*)(cbt + (size_t)t * TB + soff)        = h;
    *(bf16x8*)(cbt + (size_t)t * TB + 8192 + soff) = l;
}

// DMA one wave-quarter of tile t into LDS buffer (pure vmcnt traffic)
__device__ __forceinline__ void stage(const char* __restrict__ cbt, int t,
                                      char* dst, int w, int lane) {
    const char* src = cbt + (size_t)t * TB + w * 4096 + lane * 16;
    char* d = dst + w * 4096;
    #pragma unroll
    for (int i = 0; i < 4; ++i)
        __builtin_amdgcn_global_load_lds(
            (const __attribute__((address_space(1))) unsigned int*)(src + i * 1024),
            (__attribute__((address_space(3))) unsigned int*)(d + i * 1024),
            16, 0, 0);
}

// ---------- kernel B: 16x16x32 MFMA assign, 3-deep pipeline ----------
__global__ __launch_bounds__(256, 3) void vq_assign_kernel(const float* __restrict__ x,
                                                           const float* __restrict__ cb,
                                                           const char* __restrict__ cbt,
                                                           const float* __restrict__ c2f,
                                                           float* __restrict__ out,
                                                           int* __restrict__ cnt,
                                                           int* __restrict__ list) {
    __shared__ __attribute__((aligned(16))) char ldsbuf[3][TB];   // 48 KiB
    __shared__ float c2s[NCODE];                                  // 4 KiB

    const int tid  = threadIdx.x;
    const int lane = tid & 63;
    const int w    = tid >> 6;
    const int n0   = blockIdx.x * BMBLK;

    for (int i = tid; i < NCODE; i += 256) c2s[i] = c2f[i];

    // ---- x fragments: 16 points/wave, hi+lo, K=256 (8 chunks of 32) ----
    bf16x8 xh[8], xl[8];
    {
        const float* xrow = x + (size_t)(n0 + w * 16 + (lane & 15)) * DIMS;
        const int ks = (lane >> 4) * 8;
        #pragma unroll
        for (int kc = 0; kc < 8; ++kc) {
            float4 a = *(const float4*)(xrow + kc * 32 + ks);
            float4 b = *(const float4*)(xrow + kc * 32 + ks + 4);
            cvt8s(a, b, 1.0f, xh[kc], xl[kc]);
        }
    }

    // ---- prologue: fill pipeline with tiles 0 and 1 ----
    stage(cbt, 0, ldsbuf[0], w, lane);
    stage(cbt, 1, ldsbuf[1], w, lane);
    asm volatile("s_waitcnt vmcnt(4)" ::: "memory");   // tile 0 landed
    __builtin_amdgcn_sched_barrier(0);
    __builtin_amdgcn_s_barrier();
    __builtin_amdgcn_sched_barrier(0);

    float tb1 = FLTMAX, tb2 = FLTMAX;
    int   ti1 = 0,      ti2 = 0;

    const int r  = lane & 15;            // A-frag row (code within tile)
    const int sl = lane >> 4;            // k-slice
    const int rowbase = r * 512 + sl * 16;
    const int sw = (r & 7) << 4;

    int bsel = 0;                        // t % 3
    for (int t = 0; t < NT; ++t) {
        if (t + 2 < NT) {                // keep 2 tiles in flight
            int nb = bsel + 2; if (nb >= 3) nb -= 3;
            stage(cbt, t + 2, ldsbuf[nb], w, lane);
        }

        const char* bh = &ldsbuf[bsel][0];
        const char* bl = &ldsbuf[bsel][8192];

        // C/D: col = lane&15 (point), row = sl*4 + j (code)  [m89]
        const int cb0 = t * 16 + sl * 4;
        float4 cs = *(const float4*)&c2s[cb0];        // lgkm domain
        f32x4 a0 = { cs.x, cs.y, cs.z, cs.w };
        f32x4 a1 = { 0.f, 0.f, 0.f, 0.f };
        f32x4 a2 = { 0.f, 0.f, 0.f, 0.f };

        #pragma unroll
        for (int kc = 0; kc < 8; ++kc) {
            const int byt = (rowbase + kc * 64) ^ sw;
            bf16x8 ch = *(const bf16x8*)(bh + byt);
            bf16x8 cl = *(const bf16x8*)(bl + byt);
            a0 = __builtin_amdgcn_mfma_f32_16x16x32_bf16(ch, xh[kc], a0, 0, 0, 0);
            a1 = __builtin_amdgcn_mfma_f32_16x16x32_bf16(ch, xl[kc], a1, 0, 0, 0);
            a2 = __builtin_amdgcn_mfma_f32_16x16x32_bf16(cl, xh[kc], a2, 0, 0, 0);
        }

        // ---- epilogue: m = c2 - 2*x.c, running top-2 (codes ascend) ----
        #pragma unroll
        for (int j = 0; j < 4; ++j) {
            const int code = cb0 + j;
            float m = (a0[j] + a1[j]) + a2[j];
            if (m < tb1)      { tb2 = tb1; ti2 = ti1; tb1 = m; ti1 = code; }
            else if (m < tb2) { tb2 = m; ti2 = code; }
        }

        // ---- counted-vmcnt barrier: retire DMA(t+1), keep DMA(t+2) flying ----
        if (t + 2 < NT) {
            asm volatile("s_waitcnt vmcnt(4)" ::: "memory");
        } else if (t + 1 < NT) {
            asm volatile("s_waitcnt vmcnt(0)" ::: "memory");
        }
        if (t + 1 < NT) {
            __builtin_amdgcn_sched_barrier(0);
            __builtin_amdgcn_s_barrier();
            __builtin_amdgcn_sched_barrier(0);
        }
        bsel = (bsel + 1 == 3) ? 0 : bsel + 1;
    }

    // ---- merge across lanes {p, p+16, p+32, p+48} (disjoint code subsets) ----
    #pragma unroll
    for (int off = 16; off <= 32; off <<= 1) {
        float ob1 = __shfl_xor(tb1, off, 64);
        int   oi1 = __shfl_xor(ti1, off, 64);
        float ob2 = __shfl_xor(tb2, off, 64);
        int   oi2 = __shfl_xor(ti2, off, 64);
        float nb1, ca, cs2; int ni1, cai, csi;
        bool oless = (ob1 < tb1) || (ob1 == tb1 && oi1 < ti1);
        if (oless) { nb1 = ob1; ni1 = oi1; ca = tb1; cai = ti1; cs2 = ob2; csi = oi2; }
        else       { nb1 = tb1; ni1 = ti1; ca = ob1; cai = oi1; cs2 = tb2; csi = ti2; }
        if (cs2 < ca || (cs2 == ca && csi < cai)) { tb2 = cs2; ti2 = csi; }
        else                                      { tb2 = ca;  ti2 = cai; }
        tb1 = nb1; ti1 = ni1;
    }

    if (lane < 16) {
        const int lp = w * 16 + lane;
        if (tb2 - tb1 < EPS_FLAG) {
            int pos = atomicAdd(cnt, 1);
            list[pos] = n0 + lp;
        }
    }

    // ---- wave-local gather: out[point p] = codebook[bidx] ----
    #pragma unroll 4
    for (int p = 0; p < 16; ++p) {
        const int row = __shfl(ti1, p, 64);       // all lanes hold point p's best at lane p
        const float4* srcr = (const float4*)(cb + (size_t)row * DIMS);
        float4*       dstr = (float4*)(out + (size_t)(n0 + w * 16 + p) * DIMS);
        dstr[lane] = srcr[lane];                  // 64 lanes x 16B = 1 row
    }
}

// ---------- kernel C: exact fp64 re-check (round-6 semantics) ----------
__global__ __launch_bounds__(256) void vq_refine_kernel(const float* __restrict__ x,
                                                        const float* __restrict__ cb,
                                                        const int* __restrict__ cnt,
                                                        const int* __restrict__ list,
                                                        float* __restrict__ out) {
    __shared__ double xsd[DIMS];
    __shared__ double lb1[256], lb2[256];
    __shared__ int    li1[256], li2[256];
    __shared__ int    sel;

    const int tid = threadIdx.x;
    const int count = cnt[0];

    for (int li = blockIdx.x; li < count; li += gridDim.x) {
        const int n = list[li];
        xsd[tid] = (double)x[(size_t)n * DIMS + tid];
        __syncthreads();

        double b1 = 1.0e300, b2 = 1.0e300;
        int    j1 = 0,       j2 = 0;
        const int k0 = tid * 4;                  // ascending codes per thread
        #pragma unroll
        for (int j = 0; j < 4; ++j) {
            const int k = k0 + j;
            const float* cr = cb + (size_t)k * DIMS;
            double a0 = 0, a1 = 0, a2 = 0, a3 = 0;
            for (int d = 0; d < DIMS; d += 4) {
                double t0 = xsd[d]     - (double)cr[d];
                double t1 = xsd[d + 1] - (double)cr[d + 1];
                double t2 = xsd[d + 2] - (double)cr[d + 2];
                double t3 = xsd[d + 3] - (double)cr[d + 3];
                a0 = fma(t0, t0, a0);
                a1 = fma(t1, t1, a1);
                a2 = fma(t2, t2, a2);
                a3 = fma(t3, t3, a3);
            }
            double v = (a0 + a1) + (a2 + a3);
            if (v < b1)      { b2 = b1; j2 = j1; b1 = v; j1 = k; }
            else if (v < b2) { b2 = v; j2 = k; }
        }
        lb1[tid] = b1; li1[tid] = j1;
        lb2[tid] = b2; li2[tid] = j2;
        __syncthreads();

        if (tid == 0) {
            double B1 = 1.0e300, B2 = 1.0e300;
            int    J1 = 0,       J2 = 0;
            for (int e = 0; e < 256; ++e) {
                double v = lb1[e]; int ii = li1[e];
                if (v < B1 || (v == B1 && ii < J1)) { B2 = B1; J2 = J1; B1 = v; J1 = ii; }
                else if (v < B2 || (v == B2 && ii < J2)) { B2 = v; J2 = ii; }
                v = lb2[e]; ii = li2[e];
                if (v < B1 || (v == B1 && ii < J1)) { B2 = B1; J2 = J1; B1 = v; J1 = ii; }
                else if (v < B2 || (v == B2 && ii < J2)) { B2 = v; J2 = ii; }
            }
            sel = (B2 - B1 < TIE_TOL && J2 < J1) ? J2 : J1;
        }
        __syncthreads();

        const float4* cb4 = (const float4*)(cb + (size_t)sel * DIMS);
        float4*       o4  = (float4*)(out + (size_t)n * DIMS);
        if (tid < 64) o4[tid] = cb4[tid];
        __syncthreads();
    }
}

extern "C" void kernel_launch(void* const* d_in, const int* in_sizes, int n_in,
                              void* d_out, int out_size, void* d_ws, size_t ws_size,
                              hipStream_t stream) {
    const float* x  = (const float*)d_in[0];   // [16,4096,256]
    const float* cb = (const float*)d_in[1];   // [1024,256]
    float* out = (float*)d_out;                // [16,4096,256]

    float* c2f = (float*)d_ws;                           // 1024 floats
    int*   cnt = (int*)((char*)d_ws + 4096);             // 1 int
    int*   lst = (int*)((char*)d_ws + 4112);             // worklist
    char*  cbt = (char*)d_ws + CBT_OFF;                  // 1 MiB bf16 tiles

    vq_prep_kernel<<<128, 256, 0, stream>>>(cb, c2f, cbt, cnt);
    vq_assign_kernel<<<NPTS / BMBLK, 256, 0, stream>>>(x, cb, cbt, c2f, out, cnt, lst);
    vq_refine_kernel<<<128, 256, 0, stream>>>(x, cb, cnt, lst, out);
}

// Round 13
// 221.590 us; speedup vs baseline: 1.2020x; 1.2020x over previous
//
#include <hip/hip_runtime.h>

// VectorQuantizer: B=16, T=4096, D=256, K=1024 (fp32 in/out)
// N = B*T = 65536. out[n] = codebook[argmin_k ||x_n - c_k||^2]
//
// Two-tier (verified R6..R11 semantics):
//   1) bf16 MFMA pass (16x16x32): codebook pre-scaled by -2 (exact), hi
//      bf16 only, pre-swizzled tiles staged via global_load_lds dbuf
//      (R11-proven loop). Chains (-2c)h.xh + (-2c)h.xl, chain0 seeded with
//      c2 -> m ~= c2 - 2*x.c (err sigma~0.04). Per-point top-2;
//      gap < EPS_FLAG=0.3 (~6 sigma) -> exact re-check.
//   2) fp64 refine, 4 points/pass (codebook streamed once per 4 points):
//      direct-difference, 4 strided chains (R6 order), top-2, tie rule
//      "runner-up within TIE_TOL=3.5e-5 and lower index wins".

#define DIMS   256
#define NCODE  1024
#define NPTS   65536
#define BMBLK  64           // points per block (4 waves x 16)
#define NT     64           // 16-code tiles
#define TB     8192         // bytes per tile (hi only)
#define EPS_FLAG 0.3f
#define TIE_TOL  3.5e-5
#define FLTMAX   3.402823466e+38f
#define CBT_OFF  327680     // byte offset of bf16 codebook tiles in d_ws
#define RP     4            // refine points per pass

typedef __attribute__((ext_vector_type(8))) short bf16x8;   // 4 VGPR
typedef __attribute__((ext_vector_type(4))) float f32x4;    // 4 VGPR

// float*s -> bf16 (RNE) hi + exact-residual lo
__device__ __forceinline__ void cvt8s(const float4& a, const float4& b, float s,
                                      bf16x8& h, bf16x8& l) {
    float f[8] = {a.x*s, a.y*s, a.z*s, a.w*s, b.x*s, b.y*s, b.z*s, b.w*s};
    #pragma unroll
    for (int e = 0; e < 8; ++e) {
        unsigned u  = __float_as_uint(f[e]);
        unsigned hr = u + 0x7FFFu + ((u >> 16) & 1u);
        unsigned short hs = (unsigned short)(hr >> 16);
        float hf = __uint_as_float((unsigned)hs << 16);
        float lo = f[e] - hf;                       // exact
        unsigned ul = __float_as_uint(lo);
        unsigned lr = ul + 0x7FFFu + ((ul >> 16) & 1u);
        h[e] = (short)hs;
        l[e] = (short)(lr >> 16);
    }
}

// ---------- kernel P: cnt=0 + c2 (fp64) + codebook cvt (hi) to swizzled tiles
// Tile t (16 codes, hi only): base = t*8192.
// Within: off(r,p) = (r*512 + p*16) ^ ((r&7)<<4), r = code&15, p = 8-dim chunk.
__global__ __launch_bounds__(256) void vq_prep_kernel(const float* __restrict__ cb,
                                                      float* __restrict__ c2f,
                                                      char* __restrict__ cbt,
                                                      int* __restrict__ cnt) {
    if (blockIdx.x == 0 && threadIdx.x == 0) cnt[0] = 0;
    const int chunk = blockIdx.x * 256 + threadIdx.x;    // [0, 32768)
    const int k = chunk >> 5;                            // code
    const int p = chunk & 31;                            // 8-dim chunk
    const float4* src = (const float4*)(cb + (size_t)k * DIMS + p * 8);
    float4 a = src[0], b = src[1];

    double s = (double)a.x*a.x + (double)a.y*a.y + (double)a.z*a.z + (double)a.w*a.w
             + (double)b.x*b.x + (double)b.y*b.y + (double)b.z*b.z + (double)b.w*b.w;
    #pragma unroll
    for (int off = 16; off > 0; off >>= 1) s += __shfl_xor(s, off, 64);
    if (p == 0) c2f[k] = (float)s;

    bf16x8 h, l;
    cvt8s(a, b, -2.0f, h, l);
    const int t = k >> 4, r = k & 15;
    const int soff = (r * 512 + p * 16) ^ ((r & 7) << 4);
    *(bf16x8*)(cbt + (size_t)t * TB + soff) = h;
}

// DMA one wave-quarter (2KB) of tile t into LDS buffer
__device__ __forceinline__ void stage(const char* __restrict__ cbt, int t,
                                      char* dst, int w, int lane) {
    const char* src = cbt + (size_t)t * TB + w * 2048 + lane * 16;
    char* d = dst + w * 2048;
    #pragma unroll
    for (int i = 0; i < 2; ++i)
        __builtin_amdgcn_global_load_lds(
            (const __attribute__((address_space(1))) unsigned int*)(src + i * 1024),
            (__attribute__((address_space(3))) unsigned int*)(d + i * 1024),
            16, 0, 0);
}

// ---------- kernel B: 16x16x32 MFMA assign (R11 skeleton, hi-only) ----------
__global__ __launch_bounds__(256, 4) void vq_assign_kernel(const float* __restrict__ x,
                                                           const float* __restrict__ cb,
                                                           const char* __restrict__ cbt,
                                                           const float* __restrict__ c2f,
                                                           float* __restrict__ out,
                                                           int* __restrict__ cnt,
                                                           int* __restrict__ list) {
    __shared__ __attribute__((aligned(16))) char ldsbuf[2][TB];   // 16 KiB dbuf
    __shared__ int bidx[BMBLK];

    const int tid  = threadIdx.x;
    const int lane = tid & 63;
    const int w    = tid >> 6;
    const int n0   = blockIdx.x * BMBLK;

    // ---- stage tile 0 via global_load_lds ----
    stage(cbt, 0, ldsbuf[0], w, lane);

    // ---- x fragments: 16 points/wave, hi+lo, K=256 (8 chunks of 32) ----
    bf16x8 xh[8], xl[8];
    {
        const float* xrow = x + (size_t)(n0 + w * 16 + (lane & 15)) * DIMS;
        const int ks = (lane >> 4) * 8;
        #pragma unroll
        for (int kc = 0; kc < 8; ++kc) {
            float4 a = *(const float4*)(xrow + kc * 32 + ks);
            float4 b = *(const float4*)(xrow + kc * 32 + ks + 4);
            cvt8s(a, b, 1.0f, xh[kc], xl[kc]);
        }
    }
    __syncthreads();

    float tb1 = FLTMAX, tb2 = FLTMAX;
    int   ti1 = 0,      ti2 = 0;

    const int r  = lane & 15;            // A-frag row (code within tile)
    const int sl = lane >> 4;            // k-slice
    const int rowbase = r * 512 + sl * 16;
    const int sw = (r & 7) << 4;

    for (int t = 0; t < NT; ++t) {
        const int buf = t & 1;

        if (t + 1 < NT)                  // prefetch next tile (pure DMA)
            stage(cbt, t + 1, ldsbuf[buf ^ 1], w, lane);

        const char* bh = &ldsbuf[buf][0];

        // C/D: col = lane&15 (point), row = sl*4 + j (code)  [m89]
        const int cb0 = t * 16 + sl * 4;
        float4 cs = *(const float4*)&c2f[cb0];       // L1-broadcast global read
        f32x4 a0 = { cs.x, cs.y, cs.z, cs.w };
        f32x4 a1 = { 0.f, 0.f, 0.f, 0.f };

        #pragma unroll
        for (int kc = 0; kc < 8; ++kc) {
            const int byt = (rowbase + kc * 64) ^ sw;
            bf16x8 ch = *(const bf16x8*)(bh + byt);
            a0 = __builtin_amdgcn_mfma_f32_16x16x32_bf16(ch, xh[kc], a0, 0, 0, 0);
            a1 = __builtin_amdgcn_mfma_f32_16x16x32_bf16(ch, xl[kc], a1, 0, 0, 0);
        }

        // ---- epilogue: m = c2 - 2*x.c, running top-2 (codes ascend) ----
        #pragma unroll
        for (int j = 0; j < 4; ++j) {
            const int code = cb0 + j;
            float m = a0[j] + a1[j];
            if (m < tb1)      { tb2 = tb1; ti2 = ti1; tb1 = m; ti1 = code; }
            else if (m < tb2) { tb2 = m; ti2 = code; }
        }

        __syncthreads();   // frees buf for next prefetch + drains DMA
    }

    // ---- merge across lanes {p, p+16, p+32, p+48} (disjoint code subsets) ----
    #pragma unroll
    for (int off = 16; off <= 32; off <<= 1) {
        float ob1 = __shfl_xor(tb1, off, 64);
        int   oi1 = __shfl_xor(ti1, off, 64);
        float ob2 = __shfl_xor(tb2, off, 64);
        int   oi2 = __shfl_xor(ti2, off, 64);
        float nb1, ca, cs2; int ni1, cai, csi;
        bool oless = (ob1 < tb1) || (ob1 == tb1 && oi1 < ti1);
        if (oless) { nb1 = ob1; ni1 = oi1; ca = tb1; cai = ti1; cs2 = ob2; csi = oi2; }
        else       { nb1 = tb1; ni1 = ti1; ca = ob1; cai = oi1; cs2 = tb2; csi = ti2; }
        if (cs2 < ca || (cs2 == ca && csi < cai)) { tb2 = cs2; ti2 = csi; }
        else                                      { tb2 = ca;  ti2 = cai; }
        tb1 = nb1; ti1 = ni1;
    }

    if (lane < 16) {
        const int lp = w * 16 + lane;
        bidx[lp] = ti1;
        if (tb2 - tb1 < EPS_FLAG) {
            int pos = atomicAdd(cnt, 1);
            list[pos] = n0 + lp;
        }
    }
    __syncthreads();

    // ---- provisional gather: out rows = codebook rows ----
    {
        const float4* cb4  = (const float4*)cb;
        float4*       out4 = (float4*)(out + (size_t)n0 * DIMS);
        #pragma unroll
        for (int rr = 0; rr < 16; ++rr) {
            int f  = rr * 256 + tid;     // 0..4095
            int pp = f >> 6;
            int d4 = f & 63;
            out4[f] = cb4[(size_t)bidx[pp] * 64 + d4];
        }
    }
}

// ---------- kernel C: exact fp64 re-check, RP points per codebook stream ----
__global__ __launch_bounds__(256) void vq_refine_kernel(const float* __restrict__ x,
                                                        const float* __restrict__ cb,
                                                        const int* __restrict__ cnt,
                                                        const int* __restrict__ list,
                                                        float* __restrict__ out) {
    __shared__ double xsd[RP][DIMS];          // 8 KiB
    __shared__ double wb1[RP][4], wb2[RP][4];
    __shared__ int    wi1[RP][4], wi2[RP][4];
    __shared__ int    selp[RP];

    const int tid  = threadIdx.x;
    const int lane = tid & 63;
    const int w    = tid >> 6;
    const int count = cnt[0];

    for (int base = blockIdx.x * RP; base < count; base += gridDim.x * RP) {
        const int np = min(RP, count - base);
        #pragma unroll
        for (int p = 0; p < RP; ++p) {
            const int n = list[base + (p < np ? p : 0)];
            xsd[p][tid] = (double)x[(size_t)n * DIMS + tid];
        }
        __syncthreads();

        // 4 strided fp64 chains per (point, code) — R6 summation order
        double acc[RP][4][4];
        #pragma unroll
        for (int p = 0; p < RP; ++p)
            #pragma unroll
            for (int j = 0; j < 4; ++j)
                #pragma unroll
                for (int e = 0; e < 4; ++e) acc[p][j][e] = 0.0;

        const int k0 = tid * 4;                  // ascending codes per thread
        for (int d4 = 0; d4 < 64; ++d4) {
            double xd[RP][4];
            #pragma unroll
            for (int p = 0; p < RP; ++p)
                #pragma unroll
                for (int e = 0; e < 4; ++e) xd[p][e] = xsd[p][d4 * 4 + e];
            #pragma unroll
            for (int j = 0; j < 4; ++j) {
                float4 c4 = *(const float4*)(cb + (size_t)(k0 + j) * DIMS + d4 * 4);
                const double c0 = (double)c4.x, c1 = (double)c4.y;
                const double c2_ = (double)c4.z, c3 = (double)c4.w;
                #pragma unroll
                for (int p = 0; p < RP; ++p) {
                    double t0 = xd[p][0] - c0;
                    double t1 = xd[p][1] - c1;
                    double t2 = xd[p][2] - c2_;
                    double t3 = xd[p][3] - c3;
                    acc[p][j][0] = fma(t0, t0, acc[p][j][0]);
                    acc[p][j][1] = fma(t1, t1, acc[p][j][1]);
                    acc[p][j][2] = fma(t2, t2, acc[p][j][2]);
                    acc[p][j][3] = fma(t3, t3, acc[p][j][3]);
                }
            }
        }

        // per-point: thread top-2 (j ascending), wave shfl reduce, cross-wave
        #pragma unroll
        for (int p = 0; p < RP; ++p) {
            double b1 = 1.0e300, b2 = 1.0e300;
            int    i1 = 0,       i2 = 0;
            #pragma unroll
            for (int j = 0; j < 4; ++j) {
                double v = (acc[p][j][0] + acc[p][j][1]) + (acc[p][j][2] + acc[p][j][3]);
                const int k = k0 + j;
                if (v < b1)      { b2 = b1; i2 = i1; b1 = v; i1 = k; }
                else if (v < b2) { b2 = v; i2 = k; }
            }
            #pragma unroll
            for (int off = 1; off < 64; off <<= 1) {
                double ob1 = __shfl_xor(b1, off, 64);
                int    oi1 = __shfl_xor(i1, off, 64);
                double ob2 = __shfl_xor(b2, off, 64);
                int    oi2 = __shfl_xor(i2, off, 64);
                double nb1, ca, cs; int ni1, cai, csi;
                bool oless = (ob1 < b1) || (ob1 == b1 && oi1 < i1);
                if (oless) { nb1 = ob1; ni1 = oi1; ca = b1; cai = i1; cs = ob2; csi = oi2; }
                else       { nb1 = b1;  ni1 = i1;  ca = ob1; cai = oi1; cs = b2; csi = i2; }
                if (cs < ca || (cs == ca && csi < cai)) { b2 = cs; i2 = csi; }
                else                                    { b2 = ca; i2 = cai; }
                b1 = nb1; i1 = ni1;
            }
            if (lane == 0) { wb1[p][w] = b1; wi1[p][w] = i1; wb2[p][w] = b2; wi2[p][w] = i2; }
        }
        __syncthreads();

        if (tid == 0) {
            #pragma unroll
            for (int p = 0; p < RP; ++p) {
                double B1 = 1.0e300, B2 = 1.0e300;
                int    J1 = 0,       J2 = 0;
                for (int g = 0; g < 4; ++g) {
                    double v = wb1[p][g]; int ii = wi1[p][g];
                    if (v < B1 || (v == B1 && ii < J1)) { B2 = B1; J2 = J1; B1 = v; J1 = ii; }
                    else if (v < B2 || (v == B2 && ii < J2)) { B2 = v; J2 = ii; }
                    v = wb2[p][g]; ii = wi2[p][g];
                    if (v < B1 || (v == B1 && ii < J1)) { B2 = B1; J2 = J1; B1 = v; J1 = ii; }
                    else if (v < B2 || (v == B2 && ii < J2)) { B2 = v; J2 = ii; }
                }
                selp[p] = (B2 - B1 < TIE_TOL && J2 < J1) ? J2 : J1;
            }
        }
        __syncthreads();

        for (int p = 0; p < np; ++p) {
            const int n   = list[base + p];
            const int sel = selp[p];
            out[(size_t)n * DIMS + tid] = cb[(size_t)sel * DIMS + tid];
        }
        __syncthreads();   // protect xsd before next pass
    }
}

extern "C" void kernel_launch(void* const* d_in, const int* in_sizes, int n_in,
                              void* d_out, int out_size, void* d_ws, size_t ws_size,
                              hipStream_t stream) {
    const float* x  = (const float*)d_in[0];   // [16,4096,256]
    const float* cb = (const float*)d_in[1];   // [1024,256]
    float* out = (float*)d_out;                // [16,4096,256]

    float* c2f = (float*)d_ws;                           // 1024 floats
    int*   cnt = (int*)((char*)d_ws + 4096);             // 1 int
    int*   lst = (int*)((char*)d_ws + 4112);             // worklist
    char*  cbt = (char*)d_ws + CBT_OFF;                  // 512 KiB bf16 hi tiles

    vq_prep_kernel<<<128, 256, 0, stream>>>(cb, c2f, cbt, cnt);
    vq_assign_kernel<<<NPTS / BMBLK, 256, 0, stream>>>(x, cb, cbt, c2f, out, cnt, lst);
    vq_refine_kernel<<<512, 256, 0, stream>>>(x, cb, cnt, lst, out);
}

// Round 14
// 211.345 us; speedup vs baseline: 1.2603x; 1.0485x over previous
//
#include <hip/hip_runtime.h>

// VectorQuantizer: B=16, T=4096, D=256, K=1024 (fp32 in/out)
// N = B*T = 65536. out[n] = codebook[argmin_k ||x_n - c_k||^2]
//
// Two-tier (verified R6..R13 semantics):
//   1) bf16-split MFMA pass (16x16x32, R11-proven 3-chain numerics on the
//      R13-lean skeleton): codebook pre-scaled by -2 (exact), hi+lo bf16,
//      pre-swizzled tiles staged via global_load_lds dbuf. Chains
//      (-2c)h.xh + (-2c)h.xl + (-2c)l.xh, chain0 seeded with c2 ->
//      m = c2 - 2*x.c (err sigma ~8e-5). Per-point top-2;
//      gap < EPS_FLAG=8e-3 (R11-proven) -> exact re-check (~50 points).
//   2) fp64 refine (R8-style per-point, fast at small counts): direct-
//      difference, top-2, tie rule "runner-up within TIE_TOL=3.5e-5 and
//      lower index wins" (round-6 verified).

#define DIMS   256
#define NCODE  1024
#define NPTS   65536
#define BMBLK  64           // points per block (4 waves x 16)
#define NT     64           // 16-code tiles
#define TB     16384        // bytes per tile (hi 8K + lo 8K)
#define EPS_FLAG 8.0e-3f
#define TIE_TOL  3.5e-5
#define FLTMAX   3.402823466e+38f
#define CBT_OFF  327680     // byte offset of bf16 codebook tiles in d_ws

typedef __attribute__((ext_vector_type(8))) short bf16x8;   // 4 VGPR
typedef __attribute__((ext_vector_type(4))) float f32x4;    // 4 VGPR

// float*s -> bf16 (RNE) hi + exact-residual lo
__device__ __forceinline__ void cvt8s(const float4& a, const float4& b, float s,
                                      bf16x8& h, bf16x8& l) {
    float f[8] = {a.x*s, a.y*s, a.z*s, a.w*s, b.x*s, b.y*s, b.z*s, b.w*s};
    #pragma unroll
    for (int e = 0; e < 8; ++e) {
        unsigned u  = __float_as_uint(f[e]);
        unsigned hr = u + 0x7FFFu + ((u >> 16) & 1u);
        unsigned short hs = (unsigned short)(hr >> 16);
        float hf = __uint_as_float((unsigned)hs << 16);
        float lo = f[e] - hf;                       // exact
        unsigned ul = __float_as_uint(lo);
        unsigned lr = ul + 0x7FFFu + ((ul >> 16) & 1u);
        h[e] = (short)hs;
        l[e] = (short)(lr >> 16);
    }
}

// ---------- kernel P: cnt=0 + c2 (fp64) + codebook cvt to swizzled tiles ----
// Tile t (16 codes): base = t*16384; hi [0,8192), lo [8192,16384).
// Within: off(r,p) = (r*512 + p*16) ^ ((r&7)<<4), r = code&15, p = 8-dim chunk.
__global__ __launch_bounds__(256) void vq_prep_kernel(const float* __restrict__ cb,
                                                      float* __restrict__ c2f,
                                                      char* __restrict__ cbt,
                                                      int* __restrict__ cnt) {
    if (blockIdx.x == 0 && threadIdx.x == 0) cnt[0] = 0;
    const int chunk = blockIdx.x * 256 + threadIdx.x;    // [0, 32768)
    const int k = chunk >> 5;                            // code
    const int p = chunk & 31;                            // 8-dim chunk
    const float4* src = (const float4*)(cb + (size_t)k * DIMS + p * 8);
    float4 a = src[0], b = src[1];

    double s = (double)a.x*a.x + (double)a.y*a.y + (double)a.z*a.z + (double)a.w*a.w
             + (double)b.x*b.x + (double)b.y*b.y + (double)b.z*b.z + (double)b.w*b.w;
    #pragma unroll
    for (int off = 16; off > 0; off >>= 1) s += __shfl_xor(s, off, 64);
    if (p == 0) c2f[k] = (float)s;

    bf16x8 h, l;
    cvt8s(a, b, -2.0f, h, l);
    const int t = k >> 4, r = k & 15;
    const int soff = (r * 512 + p * 16) ^ ((r & 7) << 4);
    *(bf16x8*)(cbt + (size_t)t * TB + soff)        = h;
    *(bf16x8*)(cbt + (size_t)t * TB + 8192 + soff) = l;
}

// DMA one wave-quarter (4KB) of tile t into LDS buffer
__device__ __forceinline__ void stage(const char* __restrict__ cbt, int t,
                                      char* dst, int w, int lane) {
    const char* src = cbt + (size_t)t * TB + w * 4096 + lane * 16;
    char* d = dst + w * 4096;
    #pragma unroll
    for (int i = 0; i < 4; ++i)
        __builtin_amdgcn_global_load_lds(
            (const __attribute__((address_space(1))) unsigned int*)(src + i * 1024),
            (__attribute__((address_space(3))) unsigned int*)(d + i * 1024),
            16, 0, 0);
}

// ---------- kernel B: 16x16x32 MFMA assign, 3 chains, lean skeleton ----------
__global__ __launch_bounds__(256, 4) void vq_assign_kernel(const float* __restrict__ x,
                                                           const float* __restrict__ cb,
                                                           const char* __restrict__ cbt,
                                                           const float* __restrict__ c2f,
                                                           float* __restrict__ out,
                                                           int* __restrict__ cnt,
                                                           int* __restrict__ list) {
    __shared__ __attribute__((aligned(16))) char ldsbuf[2][TB];   // 32 KiB dbuf

    const int tid  = threadIdx.x;
    const int lane = tid & 63;
    const int w    = tid >> 6;
    const int n0   = blockIdx.x * BMBLK;

    // ---- stage tile 0 via global_load_lds ----
    stage(cbt, 0, ldsbuf[0], w, lane);

    // ---- x fragments: 16 points/wave, hi+lo, K=256 (8 chunks of 32) ----
    bf16x8 xh[8], xl[8];
    {
        const float* xrow = x + (size_t)(n0 + w * 16 + (lane & 15)) * DIMS;
        const int ks = (lane >> 4) * 8;
        #pragma unroll
        for (int kc = 0; kc < 8; ++kc) {
            float4 a = *(const float4*)(xrow + kc * 32 + ks);
            float4 b = *(const float4*)(xrow + kc * 32 + ks + 4);
            cvt8s(a, b, 1.0f, xh[kc], xl[kc]);
        }
    }
    __syncthreads();

    float tb1 = FLTMAX, tb2 = FLTMAX;
    int   ti1 = 0,      ti2 = 0;

    const int r  = lane & 15;            // A-frag row (code within tile)
    const int sl = lane >> 4;            // k-slice
    const int rowbase = r * 512 + sl * 16;
    const int sw = (r & 7) << 4;

    for (int t = 0; t < NT; ++t) {
        const int buf = t & 1;

        if (t + 1 < NT)                  // prefetch next tile (pure DMA)
            stage(cbt, t + 1, ldsbuf[buf ^ 1], w, lane);

        const char* bh = &ldsbuf[buf][0];
        const char* bl = &ldsbuf[buf][8192];

        // C/D: col = lane&15 (point), row = sl*4 + j (code)  [m89]
        const int cb0 = t * 16 + sl * 4;
        float4 cs = *(const float4*)&c2f[cb0];       // L1-broadcast global read
        f32x4 a0 = { cs.x, cs.y, cs.z, cs.w };
        f32x4 a1 = { 0.f, 0.f, 0.f, 0.f };
        f32x4 a2 = { 0.f, 0.f, 0.f, 0.f };

        #pragma unroll
        for (int kc = 0; kc < 8; ++kc) {
            const int byt = (rowbase + kc * 64) ^ sw;
            bf16x8 ch = *(const bf16x8*)(bh + byt);
            bf16x8 cl = *(const bf16x8*)(bl + byt);
            a0 = __builtin_amdgcn_mfma_f32_16x16x32_bf16(ch, xh[kc], a0, 0, 0, 0);
            a1 = __builtin_amdgcn_mfma_f32_16x16x32_bf16(ch, xl[kc], a1, 0, 0, 0);
            a2 = __builtin_amdgcn_mfma_f32_16x16x32_bf16(cl, xh[kc], a2, 0, 0, 0);
        }

        // ---- epilogue: m = c2 - 2*x.c (R11 order), running top-2 ----
        #pragma unroll
        for (int j = 0; j < 4; ++j) {
            const int code = cb0 + j;
            float m = (a0[j] + a1[j]) + a2[j];
            if (m < tb1)      { tb2 = tb1; ti2 = ti1; tb1 = m; ti1 = code; }
            else if (m < tb2) { tb2 = m; ti2 = code; }
        }

        __syncthreads();   // frees buf for next prefetch + drains DMA
    }

    // ---- merge across lanes {p, p+16, p+32, p+48} (disjoint code subsets) ----
    #pragma unroll
    for (int off = 16; off <= 32; off <<= 1) {
        float ob1 = __shfl_xor(tb1, off, 64);
        int   oi1 = __shfl_xor(ti1, off, 64);
        float ob2 = __shfl_xor(tb2, off, 64);
        int   oi2 = __shfl_xor(ti2, off, 64);
        float nb1, ca, cs2; int ni1, cai, csi;
        bool oless = (ob1 < tb1) || (ob1 == tb1 && oi1 < ti1);
        if (oless) { nb1 = ob1; ni1 = oi1; ca = tb1; cai = ti1; cs2 = ob2; csi = oi2; }
        else       { nb1 = tb1; ni1 = ti1; ca = ob1; cai = oi1; cs2 = tb2; csi = ti2; }
        if (cs2 < ca || (cs2 == ca && csi < cai)) { tb2 = cs2; ti2 = csi; }
        else                                      { tb2 = ca;  ti2 = cai; }
        tb1 = nb1; ti1 = ni1;
    }

    if (lane < 16) {
        const int lp = w * 16 + lane;
        if (tb2 - tb1 < EPS_FLAG) {
            int pos = atomicAdd(cnt, 1);
            list[pos] = n0 + lp;
        }
    }

    // ---- wave-local gather (R12-proven): out[point p] = codebook[best] ----
    #pragma unroll 4
    for (int p = 0; p < 16; ++p) {
        const int row = __shfl(ti1, p, 64);
        const float4* srcr = (const float4*)(cb + (size_t)row * DIMS);
        float4*       dstr = (float4*)(out + (size_t)(n0 + w * 16 + p) * DIMS);
        dstr[lane] = srcr[lane];                  // 64 lanes x 16B = 1 row
    }
}

// ---------- kernel C: exact fp64 re-check (R8-style, round-6 semantics) ----
__global__ __launch_bounds__(256) void vq_refine_kernel(const float* __restrict__ x,
                                                        const float* __restrict__ cb,
                                                        const int* __restrict__ cnt,
                                                        const int* __restrict__ list,
                                                        float* __restrict__ out) {
    __shared__ double xsd[DIMS];
    __shared__ double lb1[256], lb2[256];
    __shared__ int    li1[256], li2[256];
    __shared__ int    sel;

    const int tid = threadIdx.x;
    const int count = cnt[0];

    for (int li = blockIdx.x; li < count; li += gridDim.x) {
        const int n = list[li];
        xsd[tid] = (double)x[(size_t)n * DIMS + tid];
        __syncthreads();

        double b1 = 1.0e300, b2 = 1.0e300;
        int    j1 = 0,       j2 = 0;
        const int k0 = tid * 4;                  // ascending codes per thread
        #pragma unroll
        for (int j = 0; j < 4; ++j) {
            const int k = k0 + j;
            const float* cr = cb + (size_t)k * DIMS;
            double a0 = 0, a1 = 0, a2 = 0, a3 = 0;
            for (int d = 0; d < DIMS; d += 4) {
                double t0 = xsd[d]     - (double)cr[d];
                double t1 = xsd[d + 1] - (double)cr[d + 1];
                double t2 = xsd[d + 2] - (double)cr[d + 2];
                double t3 = xsd[d + 3] - (double)cr[d + 3];
                a0 = fma(t0, t0, a0);
                a1 = fma(t1, t1, a1);
                a2 = fma(t2, t2, a2);
                a3 = fma(t3, t3, a3);
            }
            double v = (a0 + a1) + (a2 + a3);
            if (v < b1)      { b2 = b1; j2 = j1; b1 = v; j1 = k; }
            else if (v < b2) { b2 = v; j2 = k; }
        }
        lb1[tid] = b1; li1[tid] = j1;
        lb2[tid] = b2; li2[tid] = j2;
        __syncthreads();

        if (tid == 0) {
            double B1 = 1.0e300, B2 = 1.0e300;
            int    J1 = 0,       J2 = 0;
            for (int e = 0; e < 256; ++e) {
                double v = lb1[e]; int ii = li1[e];
                if (v < B1 || (v == B1 && ii < J1)) { B2 = B1; J2 = J1; B1 = v; J1 = ii; }
                else if (v < B2 || (v == B2 && ii < J2)) { B2 = v; J2 = ii; }
                v = lb2[e]; ii = li2[e];
                if (v < B1 || (v == B1 && ii < J1)) { B2 = B1; J2 = J1; B1 = v; J1 = ii; }
                else if (v < B2 || (v == B2 && ii < J2)) { B2 = v; J2 = ii; }
            }
            sel = (B2 - B1 < TIE_TOL && J2 < J1) ? J2 : J1;
        }
        __syncthreads();

        const float4* cb4 = (const float4*)(cb + (size_t)sel * DIMS);
        float4*       o4  = (float4*)(out + (size_t)n * DIMS);
        if (tid < 64) o4[tid] = cb4[tid];
        __syncthreads();
    }
}

extern "C" void kernel_launch(void* const* d_in, const int* in_sizes, int n_in,
                              void* d_out, int out_size, void* d_ws, size_t ws_size,
                              hipStream_t stream) {
    const float* x  = (const float*)d_in[0];   // [16,4096,256]
    const float* cb = (const float*)d_in[1];   // [1024,256]
    float* out = (float*)d_out;                // [16,4096,256]

    float* c2f = (float*)d_ws;                           // 1024 floats
    int*   cnt = (int*)((char*)d_ws + 4096);             // 1 int
    int*   lst = (int*)((char*)d_ws + 4112);             // worklist
    char*  cbt = (char*)d_ws + CBT_OFF;                  // 1 MiB bf16 tiles

    vq_prep_kernel<<<128, 256, 0, stream>>>(cb, c2f, cbt, cnt);
    vq_assign_kernel<<<NPTS / BMBLK, 256, 0, stream>>>(x, cb, cbt, c2f, out, cnt, lst);
    vq_refine_kernel<<<128, 256, 0, stream>>>(x, cb, cnt, lst, out);
}

// Round 15
// 207.746 us; speedup vs baseline: 1.2821x; 1.0173x over previous
//
#include <hip/hip_runtime.h>

// VectorQuantizer: B=16, T=4096, D=256, K=1024 (fp32 in/out)
// N = B*T = 65536. out[n] = codebook[argmin_k ||x_n - c_k||^2]
//
// Two-tier (verified R6..R14 semantics):
//   1) bf16-split MFMA pass (16x16x32, R11 3-chain numerics, 32 pts/wave):
//      codebook pre-scaled by -2 (exact), hi+lo bf16, pre-swizzled tiles
//      staged via global_load_lds dbuf. Each ch/cl LDS read feeds TWO
//      16-point groups (6 MFMAs) -> LDS traffic per point halved.
//      Chains (-2c)h.xh + (-2c)h.xl + (-2c)l.xh, chain0 seeded with c2 ->
//      m = c2 - 2*x.c (err sigma ~1e-4). Per-point top-2;
//      gap < EPS_FLAG=8e-3 -> exact re-check (~130 points).
//   2) fp64 refine (R8-style per-point): direct-difference, top-2, tie rule
//      "runner-up within TIE_TOL=3.5e-5 and lower index wins" (R6-verified).

#define DIMS   256
#define NCODE  1024
#define NPTS   65536
#define BMBLK  128          // points per block (4 waves x 32)
#define NT     64           // 16-code tiles
#define TB     16384        // bytes per tile (hi 8K + lo 8K)
#define EPS_FLAG 8.0e-3f
#define TIE_TOL  3.5e-5
#define FLTMAX   3.402823466e+38f
#define CBT_OFF  327680     // byte offset of bf16 codebook tiles in d_ws

typedef __attribute__((ext_vector_type(8))) short bf16x8;   // 4 VGPR
typedef __attribute__((ext_vector_type(4))) float f32x4;    // 4 VGPR

// float*s -> bf16 (RNE) hi + exact-residual lo
__device__ __forceinline__ void cvt8s(const float4& a, const float4& b, float s,
                                      bf16x8& h, bf16x8& l) {
    float f[8] = {a.x*s, a.y*s, a.z*s, a.w*s, b.x*s, b.y*s, b.z*s, b.w*s};
    #pragma unroll
    for (int e = 0; e < 8; ++e) {
        unsigned u  = __float_as_uint(f[e]);
        unsigned hr = u + 0x7FFFu + ((u >> 16) & 1u);
        unsigned short hs = (unsigned short)(hr >> 16);
        float hf = __uint_as_float((unsigned)hs << 16);
        float lo = f[e] - hf;                       // exact
        unsigned ul = __float_as_uint(lo);
        unsigned lr = ul + 0x7FFFu + ((ul >> 16) & 1u);
        h[e] = (short)hs;
        l[e] = (short)(lr >> 16);
    }
}

// lexicographic top-2 merge across lane groups {p, p+16, p+32, p+48}
__device__ __forceinline__ void merge16(float& tb1, int& ti1, float& tb2, int& ti2) {
    #pragma unroll
    for (int off = 16; off <= 32; off <<= 1) {
        float ob1 = __shfl_xor(tb1, off, 64);
        int   oi1 = __shfl_xor(ti1, off, 64);
        float ob2 = __shfl_xor(tb2, off, 64);
        int   oi2 = __shfl_xor(ti2, off, 64);
        float nb1, ca, cs2; int ni1, cai, csi;
        bool oless = (ob1 < tb1) || (ob1 == tb1 && oi1 < ti1);
        if (oless) { nb1 = ob1; ni1 = oi1; ca = tb1; cai = ti1; cs2 = ob2; csi = oi2; }
        else       { nb1 = tb1; ni1 = ti1; ca = ob1; cai = oi1; cs2 = tb2; csi = ti2; }
        if (cs2 < ca || (cs2 == ca && csi < cai)) { tb2 = cs2; ti2 = csi; }
        else                                      { tb2 = ca;  ti2 = cai; }
        tb1 = nb1; ti1 = ni1;
    }
}

// ---------- kernel P: cnt=0 + c2 (fp64) + codebook cvt to swizzled tiles ----
// Tile t (16 codes): base = t*16384; hi [0,8192), lo [8192,16384).
// Within: off(r,p) = (r*512 + p*16) ^ ((r&7)<<4), r = code&15, p = 8-dim chunk.
__global__ __launch_bounds__(256) void vq_prep_kernel(const float* __restrict__ cb,
                                                      float* __restrict__ c2f,
                                                      char* __restrict__ cbt,
                                                      int* __restrict__ cnt) {
    if (blockIdx.x == 0 && threadIdx.x == 0) cnt[0] = 0;
    const int chunk = blockIdx.x * 256 + threadIdx.x;    // [0, 32768)
    const int k = chunk >> 5;                            // code
    const int p = chunk & 31;                            // 8-dim chunk
    const float4* src = (const float4*)(cb + (size_t)k * DIMS + p * 8);
    float4 a = src[0], b = src[1];

    double s = (double)a.x*a.x + (double)a.y*a.y + (double)a.z*a.z + (double)a.w*a.w
             + (double)b.x*b.x + (double)b.y*b.y + (double)b.z*b.z + (double)b.w*b.w;
    #pragma unroll
    for (int off = 16; off > 0; off >>= 1) s += __shfl_xor(s, off, 64);
    if (p == 0) c2f[k] = (float)s;

    bf16x8 h, l;
    cvt8s(a, b, -2.0f, h, l);
    const int t = k >> 4, r = k & 15;
    const int soff = (r * 512 + p * 16) ^ ((r & 7) << 4);
    *(bf16x8*)(cbt + (size_t)t * TB + soff)        = h;
    *(bf16x8*)(cbt + (size_t)t * TB + 8192 + soff) = l;
}

// DMA one wave-quarter (4KB) of tile t into LDS buffer
__device__ __forceinline__ void stage(const char* __restrict__ cbt, int t,
                                      char* dst, int w, int lane) {
    const char* src = cbt + (size_t)t * TB + w * 4096 + lane * 16;
    char* d = dst + w * 4096;
    #pragma unroll
    for (int i = 0; i < 4; ++i)
        __builtin_amdgcn_global_load_lds(
            (const __attribute__((address_space(1))) unsigned int*)(src + i * 1024),
            (__attribute__((address_space(3))) unsigned int*)(d + i * 1024),
            16, 0, 0);
}

// ---------- kernel B: 16x16x32 MFMA assign, 3 chains x 2 point-groups ------
__global__ __launch_bounds__(256, 2) void vq_assign_kernel(const float* __restrict__ x,
                                                           const float* __restrict__ cb,
                                                           const char* __restrict__ cbt,
                                                           const float* __restrict__ c2f,
                                                           float* __restrict__ out,
                                                           int* __restrict__ cnt,
                                                           int* __restrict__ list) {
    __shared__ __attribute__((aligned(16))) char ldsbuf[2][TB];   // 32 KiB dbuf

    const int tid  = threadIdx.x;
    const int lane = tid & 63;
    const int w    = tid >> 6;
    const int n0   = blockIdx.x * BMBLK;

    // ---- stage tile 0 via global_load_lds ----
    stage(cbt, 0, ldsbuf[0], w, lane);

    // ---- x fragments: 32 points/wave (2 groups of 16), hi+lo, K=256 ----
    bf16x8 xh0[8], xl0[8], xh1[8], xl1[8];
    {
        const float* xrow0 = x + (size_t)(n0 + w * 32 + (lane & 15)) * DIMS;
        const float* xrow1 = xrow0 + 16 * DIMS;
        const int ks = (lane >> 4) * 8;
        #pragma unroll
        for (int kc = 0; kc < 8; ++kc) {
            float4 a0_ = *(const float4*)(xrow0 + kc * 32 + ks);
            float4 b0_ = *(const float4*)(xrow0 + kc * 32 + ks + 4);
            cvt8s(a0_, b0_, 1.0f, xh0[kc], xl0[kc]);
            float4 a1_ = *(const float4*)(xrow1 + kc * 32 + ks);
            float4 b1_ = *(const float4*)(xrow1 + kc * 32 + ks + 4);
            cvt8s(a1_, b1_, 1.0f, xh1[kc], xl1[kc]);
        }
    }
    __syncthreads();

    float tb1g0 = FLTMAX, tb2g0 = FLTMAX, tb1g1 = FLTMAX, tb2g1 = FLTMAX;
    int   ti1g0 = 0, ti2g0 = 0, ti1g1 = 0, ti2g1 = 0;

    const int r  = lane & 15;            // A-frag row (code within tile)
    const int sl = lane >> 4;            // k-slice
    const int rowbase = r * 512 + sl * 16;
    const int sw = (r & 7) << 4;

    for (int t = 0; t < NT; ++t) {
        const int buf = t & 1;

        if (t + 1 < NT)                  // prefetch next tile (pure DMA)
            stage(cbt, t + 1, ldsbuf[buf ^ 1], w, lane);

        const char* bh = &ldsbuf[buf][0];
        const char* bl = &ldsbuf[buf][8192];

        // C/D: col = lane&15 (point), row = sl*4 + j (code)  [m89]
        const int cb0 = t * 16 + sl * 4;
        float4 cs = *(const float4*)&c2f[cb0];       // L1-broadcast global read
        f32x4 a0g0 = { cs.x, cs.y, cs.z, cs.w };
        f32x4 a1g0 = { 0.f, 0.f, 0.f, 0.f };
        f32x4 a2g0 = { 0.f, 0.f, 0.f, 0.f };
        f32x4 a0g1 = a0g0;
        f32x4 a1g1 = { 0.f, 0.f, 0.f, 0.f };
        f32x4 a2g1 = { 0.f, 0.f, 0.f, 0.f };

        #pragma unroll
        for (int kc = 0; kc < 8; ++kc) {
            const int byt = (rowbase + kc * 64) ^ sw;
            bf16x8 ch = *(const bf16x8*)(bh + byt);
            bf16x8 cl = *(const bf16x8*)(bl + byt);
            a0g0 = __builtin_amdgcn_mfma_f32_16x16x32_bf16(ch, xh0[kc], a0g0, 0, 0, 0);
            a0g1 = __builtin_amdgcn_mfma_f32_16x16x32_bf16(ch, xh1[kc], a0g1, 0, 0, 0);
            a1g0 = __builtin_amdgcn_mfma_f32_16x16x32_bf16(ch, xl0[kc], a1g0, 0, 0, 0);
            a1g1 = __builtin_amdgcn_mfma_f32_16x16x32_bf16(ch, xl1[kc], a1g1, 0, 0, 0);
            a2g0 = __builtin_amdgcn_mfma_f32_16x16x32_bf16(cl, xh0[kc], a2g0, 0, 0, 0);
            a2g1 = __builtin_amdgcn_mfma_f32_16x16x32_bf16(cl, xh1[kc], a2g1, 0, 0, 0);
        }

        // ---- epilogue: m = c2 - 2*x.c (R11 order), running top-2 ----
        #pragma unroll
        for (int j = 0; j < 4; ++j) {
            const int code = cb0 + j;
            float m0 = (a0g0[j] + a1g0[j]) + a2g0[j];
            if (m0 < tb1g0)      { tb2g0 = tb1g0; ti2g0 = ti1g0; tb1g0 = m0; ti1g0 = code; }
            else if (m0 < tb2g0) { tb2g0 = m0; ti2g0 = code; }
            float m1 = (a0g1[j] + a1g1[j]) + a2g1[j];
            if (m1 < tb1g1)      { tb2g1 = tb1g1; ti2g1 = ti1g1; tb1g1 = m1; ti1g1 = code; }
            else if (m1 < tb2g1) { tb2g1 = m1; ti2g1 = code; }
        }

        __syncthreads();   // frees buf for next prefetch + drains DMA
    }

    // ---- merge across lanes {p, p+16, p+32, p+48} (disjoint code subsets) ----
    merge16(tb1g0, ti1g0, tb2g0, ti2g0);
    merge16(tb1g1, ti1g1, tb2g1, ti2g1);

    if (lane < 16) {
        if (tb2g0 - tb1g0 < EPS_FLAG) {
            int pos = atomicAdd(cnt, 1);
            list[pos] = n0 + w * 32 + lane;
        }
        if (tb2g1 - tb1g1 < EPS_FLAG) {
            int pos = atomicAdd(cnt, 1);
            list[pos] = n0 + w * 32 + 16 + lane;
        }
    }

    // ---- wave-local gather: out[point] = codebook[best] ----
    #pragma unroll 4
    for (int p = 0; p < 16; ++p) {
        const int row0 = __shfl(ti1g0, p, 64);
        const float4* s0 = (const float4*)(cb + (size_t)row0 * DIMS);
        float4*       d0 = (float4*)(out + (size_t)(n0 + w * 32 + p) * DIMS);
        d0[lane] = s0[lane];
        const int row1 = __shfl(ti1g1, p, 64);
        const float4* s1 = (const float4*)(cb + (size_t)row1 * DIMS);
        float4*       d1 = (float4*)(out + (size_t)(n0 + w * 32 + 16 + p) * DIMS);
        d1[lane] = s1[lane];
    }
}

// ---------- kernel C: exact fp64 re-check (R8-style, round-6 semantics) ----
__global__ __launch_bounds__(256) void vq_refine_kernel(const float* __restrict__ x,
                                                        const float* __restrict__ cb,
                                                        const int* __restrict__ cnt,
                                                        const int* __restrict__ list,
                                                        float* __restrict__ out) {
    __shared__ double xsd[DIMS];
    __shared__ double lb1[256], lb2[256];
    __shared__ int    li1[256], li2[256];
    __shared__ int    sel;

    const int tid = threadIdx.x;
    const int count = cnt[0];

    for (int li = blockIdx.x; li < count; li += gridDim.x) {
        const int n = list[li];
        xsd[tid] = (double)x[(size_t)n * DIMS + tid];
        __syncthreads();

        double b1 = 1.0e300, b2 = 1.0e300;
        int    j1 = 0,       j2 = 0;
        const int k0 = tid * 4;                  // ascending codes per thread
        #pragma unroll
        for (int j = 0; j < 4; ++j) {
            const int k = k0 + j;
            const float* cr = cb + (size_t)k * DIMS;
            double a0 = 0, a1 = 0, a2 = 0, a3 = 0;
            for (int d = 0; d < DIMS; d += 4) {
                double t0 = xsd[d]     - (double)cr[d];
                double t1 = xsd[d + 1] - (double)cr[d + 1];
                double t2 = xsd[d + 2] - (double)cr[d + 2];
                double t3 = xsd[d + 3] - (double)cr[d + 3];
                a0 = fma(t0, t0, a0);
                a1 = fma(t1, t1, a1);
                a2 = fma(t2, t2, a2);
                a3 = fma(t3, t3, a3);
            }
            double v = (a0 + a1) + (a2 + a3);
            if (v < b1)      { b2 = b1; j2 = j1; b1 = v; j1 = k; }
            else if (v < b2) { b2 = v; j2 = k; }
        }
        lb1[tid] = b1; li1[tid] = j1;
        lb2[tid] = b2; li2[tid] = j2;
        __syncthreads();

        if (tid == 0) {
            double B1 = 1.0e300, B2 = 1.0e300;
            int    J1 = 0,       J2 = 0;
            for (int e = 0; e < 256; ++e) {
                double v = lb1[e]; int ii = li1[e];
                if (v < B1 || (v == B1 && ii < J1)) { B2 = B1; J2 = J1; B1 = v; J1 = ii; }
                else if (v < B2 || (v == B2 && ii < J2)) { B2 = v; J2 = ii; }
                v = lb2[e]; ii = li2[e];
                if (v < B1 || (v == B1 && ii < J1)) { B2 = B1; J2 = J1; B1 = v; J1 = ii; }
                else if (v < B2 || (v == B2 && ii < J2)) { B2 = v; J2 = ii; }
            }
            sel = (B2 - B1 < TIE_TOL && J2 < J1) ? J2 : J1;
        }
        __syncthreads();

        const float4* cb4 = (const float4*)(cb + (size_t)sel * DIMS);
        float4*       o4  = (float4*)(out + (size_t)n * DIMS);
        if (tid < 64) o4[tid] = cb4[tid];
        __syncthreads();
    }
}

extern "C" void kernel_launch(void* const* d_in, const int* in_sizes, int n_in,
                              void* d_out, int out_size, void* d_ws, size_t ws_size,
                              hipStream_t stream) {
    const float* x  = (const float*)d_in[0];   // [16,4096,256]
    const float* cb = (const float*)d_in[1];   // [1024,256]
    float* out = (float*)d_out;                // [16,4096,256]

    float* c2f = (float*)d_ws;                           // 1024 floats
    int*   cnt = (int*)((char*)d_ws + 4096);             // 1 int
    int*   lst = (int*)((char*)d_ws + 4112);             // worklist
    char*  cbt = (char*)d_ws + CBT_OFF;                  // 1 MiB bf16 tiles

    vq_prep_kernel<<<128, 256, 0, stream>>>(cb, c2f, cbt, cnt);
    vq_assign_kernel<<<NPTS / BMBLK, 256, 0, stream>>>(x, cb, cbt, c2f, out, cnt, lst);
    vq_refine_kernel<<<256, 256, 0, stream>>>(x, cb, cnt, lst, out);
}